// Round 8
// baseline (175.829 us; speedup 1.0000x reference)
//
#include <hip/hip_runtime.h>

typedef __attribute__((ext_vector_type(8))) short bf16x8;
typedef __attribute__((ext_vector_type(4))) float f32x4;

constexpr int Bb = 32, Cc = 256, Nn = 1024;
constexpr float EPSf = 1e-5f;
// scale 256^-0.5 with log2(e) folded in: softmax uses exp2 on pre-scaled scores
constexpr float QSCALE = 0.0625f * 1.44269504088896f;

__device__ __forceinline__ unsigned short f2bf(float f) {
  union { float f; unsigned u; } v; v.f = f;
  unsigned r = v.u + 0x7fffu + ((v.u >> 16) & 1u);
  return (unsigned short)(r >> 16);
}

__device__ __forceinline__ bf16x8 ldb8(const unsigned short* p) {
  return *reinterpret_cast<const bf16x8*>(p);
}

__device__ __forceinline__ void gload16(const void* g, void* l) {
  __builtin_amdgcn_global_load_lds((const __attribute__((address_space(1))) void*)g,
                                   (__attribute__((address_space(3))) void*)l, 16, 0, 0);
}

__device__ __forceinline__ float fexp2(float x) {
  float r;
  asm("v_exp_f32 %0, %1" : "=v"(r) : "v"(x));
  return r;
}

// ---------------- fused groupnorm (+ weight cvt piggybacked on spare blocks) ----------------
__global__ void __launch_bounds__(256) gn_cvt_kernel(
    const float* __restrict__ x, const float* __restrict__ gw, const float* __restrict__ gb,
    unsigned short* __restrict__ hT,
    const float* __restrict__ wq, const float* __restrict__ wk,
    const float* __restrict__ wv, const float* __restrict__ wo,
    unsigned short* __restrict__ wbf) {
  __shared__ float xs[8192];
  __shared__ float red[8];
  if (blockIdx.x >= 1024) {
    int i = (blockIdx.x - 1024) * 256 + threadIdx.x;
    wbf[i]          = f2bf(wq[i]);
    wbf[65536 + i]  = f2bf(wk[i]);
    wbf[131072 + i] = f2bf(wv[i]);
    wbf[196608 + i] = f2bf(wo[i]);
    return;
  }
  int b = blockIdx.x >> 5, g = blockIdx.x & 31;
  const float4* xg = (const float4*)(x + ((size_t)b * 32 + g) * 8192);
  float s = 0.f, ss = 0.f;
  for (int i = threadIdx.x; i < 2048; i += 256) {
    float4 v = xg[i];
    ((float4*)xs)[i] = v;
    s += v.x + v.y + v.z + v.w;
    ss += v.x * v.x + v.y * v.y + v.z * v.z + v.w * v.w;
  }
  for (int o = 1; o < 64; o <<= 1) { s += __shfl_xor(s, o, 64); ss += __shfl_xor(ss, o, 64); }
  int wid = threadIdx.x >> 6;
  if ((threadIdx.x & 63) == 0) { red[wid] = s; red[4 + wid] = ss; }
  __syncthreads();
  float S  = red[0] + red[1] + red[2] + red[3];
  float SS = red[4] + red[5] + red[6] + red[7];
  float mean = S * (1.f / 8192.f);
  float rstd = rsqrtf(SS * (1.f / 8192.f) - mean * mean + EPSf);
  float w8[8], b8[8];
#pragma unroll
  for (int c = 0; c < 8; ++c) {
    w8[c] = gw[g * 8 + c] * rstd;
    b8[c] = gb[g * 8 + c] - mean * w8[c];
  }
  unsigned short* ob = hT + (size_t)b * Nn * Cc + g * 8;
#pragma unroll
  for (int k = 0; k < 4; ++k) {
    int n = threadIdx.x + 256 * k;
    union { unsigned short u[8]; uint4 v; } pk;
#pragma unroll
    for (int c = 0; c < 8; ++c) pk.u[c] = f2bf(xs[c * 1024 + n] * w8[c] + b8[c]);
    *reinterpret_cast<uint4*>(ob + (size_t)n * Cc) = pk.v;
  }
}

// ---------------- bf16 GEMM tile body: D[row,col] = sum_k A[row,k]*Bt[col,k] + bias ----------------
__device__ __forceinline__ void gemm_tile(
    const unsigned short* __restrict__ A, const unsigned short* __restrict__ Bt,
    unsigned short* __restrict__ O, const float* __restrict__ bias, int biasRow,
    int lda, int ldb, int ldo, int row0base, int col0base) {
  int lane = threadIdx.x & 63, wid = threadIdx.x >> 6;
  int lr = lane & 15, lg = lane >> 4;
  int row0 = row0base + (wid >> 1) * 64;
  int col0 = col0base + (wid & 1) * 64;
  f32x4 acc[4][4] = {};
  for (int k0 = 0; k0 < 256; k0 += 32) {
    bf16x8 a[4], bb[4];
#pragma unroll
    for (int i = 0; i < 4; ++i) a[i] = ldb8(A + (size_t)(row0 + 16 * i + lr) * lda + k0 + 8 * lg);
#pragma unroll
    for (int j = 0; j < 4; ++j) bb[j] = ldb8(Bt + (size_t)(col0 + 16 * j + lr) * ldb + k0 + 8 * lg);
#pragma unroll
    for (int i = 0; i < 4; ++i)
#pragma unroll
      for (int j = 0; j < 4; ++j)
        acc[i][j] = __builtin_amdgcn_mfma_f32_16x16x32_bf16(a[i], bb[j], acc[i][j], 0, 0, 0);
  }
#pragma unroll
  for (int i = 0; i < 4; ++i)
#pragma unroll
    for (int j = 0; j < 4; ++j)
#pragma unroll
      for (int r = 0; r < 4; ++r) {
        int row = row0 + 16 * i + 4 * lg + r;
        int col = col0 + 16 * j + lr;
        float v = acc[i][j][r] + (biasRow ? bias[row] : bias[col]);
        O[(size_t)row * ldo + col] = f2bf(v);
      }
}

// K and V projections in one launch. grid (32, BG)
__global__ void __launch_bounds__(256) kv_gemm_kernel(
    const unsigned short* __restrict__ hT, const unsigned short* __restrict__ wbf,
    unsigned short* __restrict__ KT, unsigned short* __restrict__ VT,
    const float* __restrict__ bk, const float* __restrict__ bv) {
  int bz = blockIdx.y;
  const unsigned short* h = hT + (size_t)bz * Nn * Cc;
  int id = blockIdx.x;
  if (id < 16) {
    gemm_tile(h, wbf + 65536, KT + (size_t)bz * Nn * Cc, bk, 0,
              Cc, Cc, Cc, (id >> 1) * 128, (id & 1) * 128);
  } else {
    int i2 = id - 16;
    gemm_tile(wbf + 131072, h, VT + (size_t)bz * Cc * Nn, bv, 1,
              Cc, Cc, Nn, (i2 >> 3) * 128, (i2 & 7) * 128);
  }
}

// ---------------- fused Q-proj + flash attention + out-proj + residual ----------------
// grid (BG, 32) batch-major (XCD = b%8); 128 thr = 2 waves, 16 q-cols/wave, 32 cols/block.
// LDS 32KB -> 4 independent blocks per CU (4 barrier domains, 8 waves/CU).
// K staged as 16-row half-tiles double-buffered; V as 32-row tiles single-buffered
// (staged right after its PV consumption, drained by the next sub-iter barrier).
__global__ void __launch_bounds__(128, 2) attn_fused_kernel(
    const unsigned short* __restrict__ wbf, const float* __restrict__ bq,
    const float* __restrict__ bo, const unsigned short* __restrict__ hT,
    const unsigned short* __restrict__ KT, const unsigned short* __restrict__ VT,
    const float* __restrict__ x, float* __restrict__ out) {
  int b = blockIdx.x;
  int tid = threadIdx.x;
  int lane = tid & 63, wid = tid >> 6;  // wid 0..1
  int lr = lane & 15, lg = lane >> 4;
  int n0 = blockIdx.y * 32 + wid * 16;
  const unsigned short* hrow = hT + ((size_t)b * Nn + n0 + lr) * Cc;
  const char* KTb = (const char*)(KT + (size_t)b * Nn * Cc);
  const char* VTb = (const char*)(VT + (size_t)b * Cc * Nn);
  const float* xb = x + (size_t)b * Cc * Nn;
  float* ob = out + (size_t)b * Cc * Nn;

  // LDS: [0,8K) K half-tile buf0 | [8K,16K) K buf1 | [16K,32K) V tile (32 rows)
  __shared__ alignas(16) char lds[32768];

  // K half-tile: 16 rows x 512B = 8KB; source inverse-swizzled (involution, bits 4-6 by row&7)
  auto stageK = [&](int t, int buf) {
    char* kdst = lds + buf * 8192;
    const char* kg = KTb + (size_t)t * 8192;
#pragma unroll
    for (int r = 0; r < 4; ++r) {
      int Lb = r * 2048 + wid * 1024;
      int L = Lb + lane * 16;
      int lk = L ^ (((L >> 9) & 7) << 4);
      gload16(kg + lk, kdst + Lb);
    }
  };
  // V tile: 256 rows x 64B = 16KB (rows = channels, 32 m-cols); swz bits 4-5 by (row>>1)&3
  auto stageV = [&](int u) {
    char* vdst = lds + 16384;
    const char* vg = VTb + (size_t)u * 64;
#pragma unroll
    for (int r = 0; r < 8; ++r) {
      int Lb = r * 2048 + wid * 1024;
      int L = Lb + lane * 16;
      int off = (L ^ (((L >> 7) & 3) << 4)) & 63;
      gload16(vg + (size_t)(L >> 6) * 2048 + off, vdst + Lb);
    }
  };

  stageK(0, 0);
  stageV(0);

  // ---- Q projection into B-fragment registers (16 cols per wave), global-only reads
  bf16x8 q[8];
  {
    bf16x8 hfrag[8];
#pragma unroll
    for (int kk = 0; kk < 8; ++kk) hfrag[kk] = ldb8(hrow + 32 * kk + 8 * lg);
    unsigned wqp[16][2];
#pragma unroll
    for (int t = 0; t < 16; ++t) {
      f32x4 aq = {0.f, 0.f, 0.f, 0.f};
#pragma unroll
      for (int kk = 0; kk < 8; ++kk) {
        bf16x8 wf = ldb8(wbf + (size_t)(16 * t + lr) * Cc + 32 * kk + 8 * lg);
        aq = __builtin_amdgcn_mfma_f32_16x16x32_bf16(wf, hfrag[kk], aq, 0, 0, 0);
      }
      float4 bqv = *reinterpret_cast<const float4*>(bq + 16 * t + 4 * lg);
      float q0 = (aq[0] + bqv.x) * QSCALE, q1 = (aq[1] + bqv.y) * QSCALE;
      float q2 = (aq[2] + bqv.z) * QSCALE, q3 = (aq[3] + bqv.w) * QSCALE;
      asm("v_cvt_pk_bf16_f32 %0, %1, %2" : "=v"(wqp[t][0]) : "v"(q0), "v"(q1));
      asm("v_cvt_pk_bf16_f32 %0, %1, %2" : "=v"(wqp[t][1]) : "v"(q2), "v"(q3));
    }
    int srcA = lr + 16 * ((2 * lg) & 3);
    int srcB = lr + 16 * ((2 * lg + 1) & 3);
    int hi = lg >> 1;
#pragma unroll
    for (int kk = 0; kk < 8; ++kk) {
      unsigned a0 = __shfl(wqp[2 * kk][0], srcA, 64), b0 = __shfl(wqp[2 * kk + 1][0], srcA, 64);
      unsigned a1 = __shfl(wqp[2 * kk][1], srcA, 64), b1 = __shfl(wqp[2 * kk + 1][1], srcA, 64);
      unsigned a2 = __shfl(wqp[2 * kk][0], srcB, 64), b2 = __shfl(wqp[2 * kk + 1][0], srcB, 64);
      unsigned a3 = __shfl(wqp[2 * kk][1], srcB, 64), b3 = __shfl(wqp[2 * kk + 1][1], srcB, 64);
      union { unsigned w[4]; bf16x8 v; } u;
      u.w[0] = hi ? b0 : a0; u.w[1] = hi ? b1 : a1;
      u.w[2] = hi ? b2 : a2; u.w[3] = hi ? b3 : a3;
      q[kk] = u.v;
    }
  }
  __syncthreads();  // K(0)+V(0) staged (vmcnt drained at barrier)

  // QK over one 16-row K half-tile from Kb[buf]: two independent 4-deep MFMA chains
  auto qk_half = [&](int buf) -> f32x4 {
    const char* kbuf = lds + buf * 8192;
    f32x4 sa = {0.f, 0.f, 0.f, 0.f}, sb = {0.f, 0.f, 0.f, 0.f};
    int sx = (lr & 7) << 4;
    __builtin_amdgcn_s_setprio(1);
#pragma unroll
    for (int kk = 0; kk < 4; ++kk) {
      int ca = kk * 64 + lg * 16;
      int cb = (kk + 4) * 64 + lg * 16;
      bf16x8 ka = *reinterpret_cast<const bf16x8*>(kbuf + ((lr * 512 + ca) ^ sx));
      bf16x8 kb = *reinterpret_cast<const bf16x8*>(kbuf + ((lr * 512 + cb) ^ sx));
      sa = __builtin_amdgcn_mfma_f32_16x16x32_bf16(ka, q[kk], sa, 0, 0, 0);
      sb = __builtin_amdgcn_mfma_f32_16x16x32_bf16(kb, q[kk + 4], sb, 0, 0, 0);
    }
    __builtin_amdgcn_s_setprio(0);
    f32x4 st;
#pragma unroll
    for (int r = 0; r < 4; ++r) st[r] = sa[r] + sb[r];
    return st;
  };

  f32x4 acc[16] = {};
  float lsum = 0.f;
  for (int u = 0; u < 32; ++u) {
    // ---- sub-iter A: K half-tile 2u (rows 32u..32u+15)
    stageK(2 * u + 1, 1);
    f32x4 stA = qk_half(0);
    float pA[4];
#pragma unroll
    for (int r = 0; r < 4; ++r) pA[r] = fexp2(stA[r]);
    lsum += (pA[0] + pA[1]) + (pA[2] + pA[3]);
    unsigned w00, w01;
    asm("v_cvt_pk_bf16_f32 %0, %1, %2" : "=v"(w00) : "v"(pA[0]), "v"(pA[1]));
    asm("v_cvt_pk_bf16_f32 %0, %1, %2" : "=v"(w01) : "v"(pA[2]), "v"(pA[3]));
    __syncthreads();  // K(2u+1) staged; all waves done with Kb0 reads

    // ---- sub-iter B: K half-tile 2u+1 (rows 32u+16..32u+31)
    if (u < 31) stageK(2 * u + 2, 0);
    f32x4 stB = qk_half(1);
    float pB[4];
#pragma unroll
    for (int r = 0; r < 4; ++r) pB[r] = fexp2(stB[r]);
    lsum += (pB[0] + pB[1]) + (pB[2] + pB[3]);
    unsigned w10, w11;
    asm("v_cvt_pk_bf16_f32 %0, %1, %2" : "=v"(w10) : "v"(pB[0]), "v"(pB[1]));
    asm("v_cvt_pk_bf16_f32 %0, %1, %2" : "=v"(w11) : "v"(pB[2]), "v"(pB[3]));

    // ---- P redistribution (once per 32 rows): w00/w01 = rows 0-15, w10/w11 = rows 16-31
    int sl0 = lr + 16 * (2 * (lg & 1));
    int sl1 = sl0 + 16;
    int hi = lg >> 1;
    union { unsigned w[4]; bf16x8 v; } pbu;
    {
      unsigned a = __shfl(w00, sl0, 64), c = __shfl(w10, sl0, 64);
      pbu.w[0] = hi ? c : a;
      unsigned a1 = __shfl(w01, sl0, 64), c1 = __shfl(w11, sl0, 64);
      pbu.w[1] = hi ? c1 : a1;
      unsigned a2 = __shfl(w00, sl1, 64), c2 = __shfl(w10, sl1, 64);
      pbu.w[2] = hi ? c2 : a2;
      unsigned a3 = __shfl(w01, sl1, 64), c3 = __shfl(w11, sl1, 64);
      pbu.w[3] = hi ? c3 : a3;
    }
    // ---- PV from the V tile (rows 32u..32u+31)
    const char* vbuf = lds + 16384;
    __builtin_amdgcn_s_setprio(1);
#pragma unroll
    for (int tt = 0; tt < 16; ++tt) {
      int row = 16 * tt + lr;
      int ov = (row * 64 + lg * 16) ^ (((row >> 1) & 3) << 4);
      bf16x8 va = *reinterpret_cast<const bf16x8*>(vbuf + ov);
      acc[tt] = __builtin_amdgcn_mfma_f32_16x16x32_bf16(va, pbu.v, acc[tt], 0, 0, 0);
    }
    __builtin_amdgcn_s_setprio(0);
    __syncthreads();  // all waves done reading V(u); K(2u+2) drained
    if (u < 31) stageV(u + 1);  // drains at next sub-A barrier, before PV(u+1)
  }
  lsum += __shfl_xor(lsum, 16, 64);
  lsum += __shfl_xor(lsum, 32, 64);

  // ---- fused epilogue: hout -> (wo projection) + bo + x -> fp32 out
  const unsigned short* wob = wbf + 196608;
  {
    float inv = 1.f / lsum;
    unsigned hp[16][2];
#pragma unroll
    for (int tt = 0; tt < 16; ++tt) {
      float h0 = acc[tt][0] * inv, h1 = acc[tt][1] * inv;
      float h2 = acc[tt][2] * inv, h3 = acc[tt][3] * inv;
      asm("v_cvt_pk_bf16_f32 %0, %1, %2" : "=v"(hp[tt][0]) : "v"(h0), "v"(h1));
      asm("v_cvt_pk_bf16_f32 %0, %1, %2" : "=v"(hp[tt][1]) : "v"(h2), "v"(h3));
    }
    int srcA = lr + 16 * ((2 * lg) & 3);
    int srcB = lr + 16 * ((2 * lg + 1) & 3);
    int hi = lg >> 1;
    bf16x8 hb[8];
#pragma unroll
    for (int kk = 0; kk < 8; ++kk) {
      unsigned a0 = __shfl(hp[2 * kk][0], srcA, 64), b0 = __shfl(hp[2 * kk + 1][0], srcA, 64);
      unsigned a1 = __shfl(hp[2 * kk][1], srcA, 64), b1 = __shfl(hp[2 * kk + 1][1], srcA, 64);
      unsigned a2 = __shfl(hp[2 * kk][0], srcB, 64), b2 = __shfl(hp[2 * kk + 1][0], srcB, 64);
      unsigned a3 = __shfl(hp[2 * kk][1], srcB, 64), b3 = __shfl(hp[2 * kk + 1][1], srcB, 64);
      union { unsigned w[4]; bf16x8 v; } u;
      u.w[0] = hi ? b0 : a0; u.w[1] = hi ? b1 : a1;
      u.w[2] = hi ? b2 : a2; u.w[3] = hi ? b3 : a3;
      hb[kk] = u.v;
    }
    int n = n0 + lr;
#pragma unroll
    for (int t = 0; t < 16; ++t) {
      f32x4 ao = {0.f, 0.f, 0.f, 0.f};
#pragma unroll
      for (int kk = 0; kk < 8; ++kk) {
        bf16x8 wf = ldb8(wob + (size_t)(16 * t + lr) * Cc + 32 * kk + 8 * lg);
        ao = __builtin_amdgcn_mfma_f32_16x16x32_bf16(wf, hb[kk], ao, 0, 0, 0);
      }
      float4 bov = *reinterpret_cast<const float4*>(bo + 16 * t + 4 * lg);
#pragma unroll
      for (int r = 0; r < 4; ++r) {
        int o = 16 * t + 4 * lg + r;
        size_t idx = (size_t)o * Nn + n;
        ob[idx] = xb[idx] + ((const float*)&bov)[r] + ao[r];
      }
    }
  }
}

extern "C" void kernel_launch(void* const* d_in, const int* in_sizes, int n_in,
                              void* d_out, int out_size, void* d_ws, size_t ws_size,
                              hipStream_t stream) {
  const float* x  = (const float*)d_in[0];
  const float* gw = (const float*)d_in[1];
  const float* gb = (const float*)d_in[2];
  const float* wq = (const float*)d_in[3];
  const float* bq = (const float*)d_in[4];
  const float* wk = (const float*)d_in[5];
  const float* bk = (const float*)d_in[6];
  const float* wv = (const float*)d_in[7];
  const float* bv = (const float*)d_in[8];
  const float* wo = (const float*)d_in[9];
  const float* bo = (const float*)d_in[10];
  float* out = (float*)d_out;
  char* ws = (char*)d_ws;

  // workspace layout — NEVER exceed ws_size:
  //   [0, 512KB)   wbf: 4 weight matrices bf16
  //   [1MB, 17MB)  hT [B,N,C] bf16
  //   [17MB, ...)  K^T/V^T staging for BG batches (BG*1MB), BG adapted to ws_size
  unsigned short* wbf = (unsigned short*)ws;
  unsigned short* hT  = (unsigned short*)(ws + (1 << 20));
  const size_t KV_OFF = (size_t)17 << 20;
  const size_t perBatchKV = (size_t)Nn * Cc * 2 * 2;  // 1MB (KT + VT)
  size_t avail = ws_size > KV_OFF ? ws_size - KV_OFF : 0;
  int BG = 32;
  while (BG > 1 && (size_t)BG * perBatchKV > avail) BG >>= 1;

  gn_cvt_kernel<<<dim3(1280), dim3(256), 0, stream>>>(x, gw, gb, hT, wq, wk, wv, wo, wbf);

  unsigned short* KTg = (unsigned short*)(ws + KV_OFF);
  unsigned short* VTg = KTg + (size_t)BG * Nn * Cc;

  for (int g = 0; g < Bb; g += BG) {
    unsigned short* hTg = hT + (size_t)g * Nn * Cc;
    kv_gemm_kernel<<<dim3(32, BG), dim3(256), 0, stream>>>(hTg, wbf, KTg, VTg, bk, bv);
    attn_fused_kernel<<<dim3(BG, 32), dim3(128), 0, stream>>>(
        wbf, bq, bo, hTg, KTg, VTg, x + (size_t)g * Cc * Nn, out + (size_t)g * Cc * Nn);
  }
}

// Round 9
// 163.012 us; speedup vs baseline: 1.0786x; 1.0786x over previous
//
#include <hip/hip_runtime.h>

typedef __attribute__((ext_vector_type(8))) short bf16x8;
typedef __attribute__((ext_vector_type(4))) float f32x4;

constexpr int Bb = 32, Cc = 256, Nn = 1024;
constexpr float EPSf = 1e-5f;
// scale 256^-0.5 with log2(e) folded in: softmax uses exp2 on pre-scaled scores
constexpr float QSCALE = 0.0625f * 1.44269504088896f;

__device__ __forceinline__ unsigned short f2bf(float f) {
  union { float f; unsigned u; } v; v.f = f;
  unsigned r = v.u + 0x7fffu + ((v.u >> 16) & 1u);
  return (unsigned short)(r >> 16);
}

__device__ __forceinline__ bf16x8 ldb8(const unsigned short* p) {
  return *reinterpret_cast<const bf16x8*>(p);
}

__device__ __forceinline__ void gload16(const void* g, void* l) {
  __builtin_amdgcn_global_load_lds((const __attribute__((address_space(1))) void*)g,
                                   (__attribute__((address_space(3))) void*)l, 16, 0, 0);
}

__device__ __forceinline__ float fexp2(float x) {
  float r;
  asm("v_exp_f32 %0, %1" : "=v"(r) : "v"(x));
  return r;
}

// ---------------- fused groupnorm (+ weight cvt piggybacked on spare blocks) ----------------
__global__ void __launch_bounds__(256) gn_cvt_kernel(
    const float* __restrict__ x, const float* __restrict__ gw, const float* __restrict__ gb,
    unsigned short* __restrict__ hT,
    const float* __restrict__ wq, const float* __restrict__ wk,
    const float* __restrict__ wv, const float* __restrict__ wo,
    unsigned short* __restrict__ wbf) {
  __shared__ float xs[8192];
  __shared__ float red[8];
  if (blockIdx.x >= 1024) {
    int i = (blockIdx.x - 1024) * 256 + threadIdx.x;
    wbf[i]          = f2bf(wq[i]);
    wbf[65536 + i]  = f2bf(wk[i]);
    wbf[131072 + i] = f2bf(wv[i]);
    wbf[196608 + i] = f2bf(wo[i]);
    return;
  }
  int b = blockIdx.x >> 5, g = blockIdx.x & 31;
  const float4* xg = (const float4*)(x + ((size_t)b * 32 + g) * 8192);
  float s = 0.f, ss = 0.f;
  for (int i = threadIdx.x; i < 2048; i += 256) {
    float4 v = xg[i];
    ((float4*)xs)[i] = v;
    s += v.x + v.y + v.z + v.w;
    ss += v.x * v.x + v.y * v.y + v.z * v.z + v.w * v.w;
  }
  for (int o = 1; o < 64; o <<= 1) { s += __shfl_xor(s, o, 64); ss += __shfl_xor(ss, o, 64); }
  int wid = threadIdx.x >> 6;
  if ((threadIdx.x & 63) == 0) { red[wid] = s; red[4 + wid] = ss; }
  __syncthreads();
  float S  = red[0] + red[1] + red[2] + red[3];
  float SS = red[4] + red[5] + red[6] + red[7];
  float mean = S * (1.f / 8192.f);
  float rstd = rsqrtf(SS * (1.f / 8192.f) - mean * mean + EPSf);
  float w8[8], b8[8];
#pragma unroll
  for (int c = 0; c < 8; ++c) {
    w8[c] = gw[g * 8 + c] * rstd;
    b8[c] = gb[g * 8 + c] - mean * w8[c];
  }
  unsigned short* ob = hT + (size_t)b * Nn * Cc + g * 8;
#pragma unroll
  for (int k = 0; k < 4; ++k) {
    int n = threadIdx.x + 256 * k;
    union { unsigned short u[8]; uint4 v; } pk;
#pragma unroll
    for (int c = 0; c < 8; ++c) pk.u[c] = f2bf(xs[c * 1024 + n] * w8[c] + b8[c]);
    *reinterpret_cast<uint4*>(ob + (size_t)n * Cc) = pk.v;
  }
}

// ---------------- bf16 GEMM tile body: D[row,col] = sum_k A[row,k]*Bt[col,k] + bias ----------------
__device__ __forceinline__ void gemm_tile(
    const unsigned short* __restrict__ A, const unsigned short* __restrict__ Bt,
    unsigned short* __restrict__ O, const float* __restrict__ bias, int biasRow,
    int lda, int ldb, int ldo, int row0base, int col0base) {
  int lane = threadIdx.x & 63, wid = threadIdx.x >> 6;
  int lr = lane & 15, lg = lane >> 4;
  int row0 = row0base + (wid >> 1) * 64;
  int col0 = col0base + (wid & 1) * 64;
  f32x4 acc[4][4] = {};
  for (int k0 = 0; k0 < 256; k0 += 32) {
    bf16x8 a[4], bb[4];
#pragma unroll
    for (int i = 0; i < 4; ++i) a[i] = ldb8(A + (size_t)(row0 + 16 * i + lr) * lda + k0 + 8 * lg);
#pragma unroll
    for (int j = 0; j < 4; ++j) bb[j] = ldb8(Bt + (size_t)(col0 + 16 * j + lr) * ldb + k0 + 8 * lg);
#pragma unroll
    for (int i = 0; i < 4; ++i)
#pragma unroll
      for (int j = 0; j < 4; ++j)
        acc[i][j] = __builtin_amdgcn_mfma_f32_16x16x32_bf16(a[i], bb[j], acc[i][j], 0, 0, 0);
  }
#pragma unroll
  for (int i = 0; i < 4; ++i)
#pragma unroll
    for (int j = 0; j < 4; ++j)
#pragma unroll
      for (int r = 0; r < 4; ++r) {
        int row = row0 + 16 * i + 4 * lg + r;
        int col = col0 + 16 * j + lr;
        float v = acc[i][j][r] + (biasRow ? bias[row] : bias[col]);
        O[(size_t)row * ldo + col] = f2bf(v);
      }
}

// K and V projections in one launch. grid (32, BG)
__global__ void __launch_bounds__(256) kv_gemm_kernel(
    const unsigned short* __restrict__ hT, const unsigned short* __restrict__ wbf,
    unsigned short* __restrict__ KT, unsigned short* __restrict__ VT,
    const float* __restrict__ bk, const float* __restrict__ bv) {
  int bz = blockIdx.y;
  const unsigned short* h = hT + (size_t)bz * Nn * Cc;
  int id = blockIdx.x;
  if (id < 16) {
    gemm_tile(h, wbf + 65536, KT + (size_t)bz * Nn * Cc, bk, 0,
              Cc, Cc, Cc, (id >> 1) * 128, (id & 1) * 128);
  } else {
    int i2 = id - 16;
    gemm_tile(wbf + 131072, h, VT + (size_t)bz * Cc * Nn, bv, 1,
              Cc, Cc, Nn, (i2 >> 3) * 128, (i2 & 7) * 128);
  }
}

// ---------------- fused Q-proj + flash attention + out-proj + residual ----------------
// grid (BG, 16) batch-major (XCD = b%8); 256 thr = 4 waves, 16 q-cols/wave, 64 cols/block,
// 512 blocks -> 2 blocks/CU. R7 structure + T4 counted-vmcnt barriers: stage(t+1)'s
// loads stay in flight across the barrier; only stage(t) (the buffer being read) is
// awaited via s_waitcnt vmcnt(8).
__global__ void __launch_bounds__(256, 2) attn_fused_kernel(
    const unsigned short* __restrict__ wbf, const float* __restrict__ bq,
    const float* __restrict__ bo, const unsigned short* __restrict__ hT,
    const unsigned short* __restrict__ KT, const unsigned short* __restrict__ VT,
    const float* __restrict__ x, float* __restrict__ out) {
  int b = blockIdx.x;
  int tid = threadIdx.x;
  int lane = tid & 63, wid = tid >> 6;
  int lr = lane & 15, lg = lane >> 4;
  int n0 = blockIdx.y * 64 + wid * 16;
  const unsigned short* hrow = hT + ((size_t)b * Nn + n0 + lr) * Cc;  // wave's 16 rows (by lr)
  const char* KTb = (const char*)(KT + (size_t)b * Nn * Cc);
  const char* VTb = (const char*)(VT + (size_t)b * Cc * Nn);
  const float* xb = x + (size_t)b * Cc * Nn;
  float* ob = out + (size_t)b * Cc * Nn;

  // LDS: buf{0,1} of 32KB: K tile [32 rows][512B] at +0, V tile [256 rows][64B] at +16K
  __shared__ alignas(16) char lds[65536];

  // stage one 32-row KV tile cooperatively (256 thr x 8 gload16 = 32KB).
  // global_load_lds writes linearly; the read-side XOR swizzle is realized by
  // inverse-swizzling the *global source* byte address (involution).
  auto stage = [&](int t, int buf) {
    char* kdst = lds + buf * 32768;
    char* vdst = kdst + 16384;
    const char* kg = KTb + (size_t)t * 32 * 512;  // 32 rows of K^T [N,C]
    const char* vg = VTb + (size_t)t * 64;        // 32 cols (2B each) of V^T [C,N]
#pragma unroll
    for (int r = 0; r < 4; ++r) {
      int Lb = r * 4096 + wid * 1024;
      int L = Lb + lane * 16;
      int lk = L ^ (((L >> 9) & 7) << 4);                 // K: 512B rows, swz bits 4-6
      gload16(kg + lk, kdst + Lb);
      int off = (L ^ (((L >> 7) & 3) << 4)) & 63;         // V: 64B rows, swz bits 4-5
      gload16(vg + (size_t)(L >> 6) * 2048 + off, vdst + Lb);
    }
  };

  stage(0, 0);  // overlap tile-0 staging with the Q projection (no LDS use below)

  // ---- Q projection into B-fragment registers:
  // raw aq[t][r] = Q[n=lr-col][ch=16t+4lg+r]; rearrange via cvt_pk + shuffles so
  // q[kk] word wi holds the bf16 pair for ch = 32kk + 8lg + 2wi of this lane's col.
  bf16x8 q[8];
  {
    bf16x8 hfrag[8];
#pragma unroll
    for (int kk = 0; kk < 8; ++kk) hfrag[kk] = ldb8(hrow + 32 * kk + 8 * lg);
    unsigned wqp[16][2];
#pragma unroll
    for (int t = 0; t < 16; ++t) {
      f32x4 aq = {0.f, 0.f, 0.f, 0.f};
#pragma unroll
      for (int kk = 0; kk < 8; ++kk) {
        bf16x8 wf = ldb8(wbf + (size_t)(16 * t + lr) * Cc + 32 * kk + 8 * lg);
        aq = __builtin_amdgcn_mfma_f32_16x16x32_bf16(wf, hfrag[kk], aq, 0, 0, 0);
      }
      float4 bqv = *reinterpret_cast<const float4*>(bq + 16 * t + 4 * lg);
      float q0 = (aq[0] + bqv.x) * QSCALE, q1 = (aq[1] + bqv.y) * QSCALE;
      float q2 = (aq[2] + bqv.z) * QSCALE, q3 = (aq[3] + bqv.w) * QSCALE;
      asm("v_cvt_pk_bf16_f32 %0, %1, %2" : "=v"(wqp[t][0]) : "v"(q0), "v"(q1));
      asm("v_cvt_pk_bf16_f32 %0, %1, %2" : "=v"(wqp[t][1]) : "v"(q2), "v"(q3));
    }
    int srcA = lr + 16 * ((2 * lg) & 3);
    int srcB = lr + 16 * ((2 * lg + 1) & 3);
    int hi = lg >> 1;
#pragma unroll
    for (int kk = 0; kk < 8; ++kk) {
      unsigned a0 = __shfl(wqp[2 * kk][0], srcA, 64), b0 = __shfl(wqp[2 * kk + 1][0], srcA, 64);
      unsigned a1 = __shfl(wqp[2 * kk][1], srcA, 64), b1 = __shfl(wqp[2 * kk + 1][1], srcA, 64);
      unsigned a2 = __shfl(wqp[2 * kk][0], srcB, 64), b2 = __shfl(wqp[2 * kk + 1][0], srcB, 64);
      unsigned a3 = __shfl(wqp[2 * kk][1], srcB, 64), b3 = __shfl(wqp[2 * kk + 1][1], srcB, 64);
      union { unsigned w[4]; bf16x8 v; } u;
      u.w[0] = hi ? b0 : a0; u.w[1] = hi ? b1 : a1;
      u.w[2] = hi ? b2 : a2; u.w[3] = hi ? b3 : a3;
      q[kk] = u.v;
    }
  }
  __syncthreads();  // tile0 staged (full vmcnt drain) + all waves ready

  f32x4 acc[16] = {};
  float lsum = 0.f;  // per-lane partial softmax denominator (this lane's m-slice)
  for (int t = 0; t < 32; ++t) {
    int cur = t & 1;
    // issue next tile's staging, then wait ONLY for the current tile's 8 loads
    // (issued last iteration): counted vmcnt leaves stage(t+1) in flight.
    if (t < 31) {
      stage(t + 1, cur ^ 1);
      asm volatile("s_waitcnt vmcnt(8)" ::: "memory");
    } else {
      asm volatile("s_waitcnt vmcnt(0)" ::: "memory");
    }
    __builtin_amdgcn_sched_barrier(0);
    const char* kbuf = lds + cur * 32768;
    const char* vbuf = kbuf + 16384;
    // ---- QK^T from LDS (swizzled reads)
    f32x4 st0 = {0.f, 0.f, 0.f, 0.f}, st1 = {0.f, 0.f, 0.f, 0.f};
    __builtin_amdgcn_s_setprio(1);
#pragma unroll
    for (int kk = 0; kk < 8; ++kk) {
      int c = kk * 64 + lg * 16;
      int sx = (lr & 7) << 4;
      bf16x8 k0 = *reinterpret_cast<const bf16x8*>(kbuf + ((lr * 512 + c) ^ sx));
      bf16x8 k1 = *reinterpret_cast<const bf16x8*>(kbuf + (((lr + 16) * 512 + c) ^ sx));
      st0 = __builtin_amdgcn_mfma_f32_16x16x32_bf16(k0, q[kk], st0, 0, 0, 0);
      st1 = __builtin_amdgcn_mfma_f32_16x16x32_bf16(k1, q[kk], st1, 0, 0, 0);
    }
    __builtin_amdgcn_s_setprio(0);
    // lane holds S^T[m = 4lg+r (+16)][n = n0+lr], pre-scaled for exp2.
    float p0[4], p1[4];
#pragma unroll
    for (int r = 0; r < 4; ++r) {
      p0[r] = fexp2(st0[r]);
      p1[r] = fexp2(st1[r]);
    }
    lsum += ((p0[0] + p0[1]) + (p0[2] + p0[3])) + ((p1[0] + p1[1]) + (p1[2] + p1[3]));
    // ---- P -> bf16 packed + redistribute (4 cvt_pk + 8 shuffles)
    unsigned w00, w01, w10, w11;
    asm("v_cvt_pk_bf16_f32 %0, %1, %2" : "=v"(w00) : "v"(p0[0]), "v"(p0[1]));
    asm("v_cvt_pk_bf16_f32 %0, %1, %2" : "=v"(w01) : "v"(p0[2]), "v"(p0[3]));
    asm("v_cvt_pk_bf16_f32 %0, %1, %2" : "=v"(w10) : "v"(p1[0]), "v"(p1[1]));
    asm("v_cvt_pk_bf16_f32 %0, %1, %2" : "=v"(w11) : "v"(p1[2]), "v"(p1[3]));
    int sl0 = lr + 16 * (2 * (lg & 1));
    int sl1 = sl0 + 16;
    int hi = lg >> 1;
    union { unsigned w[4]; bf16x8 v; } pbu;
    {
      unsigned a = __shfl(w00, sl0, 64), c = __shfl(w10, sl0, 64);
      pbu.w[0] = hi ? c : a;
      unsigned a1 = __shfl(w01, sl0, 64), c1 = __shfl(w11, sl0, 64);
      pbu.w[1] = hi ? c1 : a1;
      unsigned a2 = __shfl(w00, sl1, 64), c2 = __shfl(w10, sl1, 64);
      pbu.w[2] = hi ? c2 : a2;
      unsigned a3 = __shfl(w01, sl1, 64), c3 = __shfl(w11, sl1, 64);
      pbu.w[3] = hi ? c3 : a3;
    }
    // ---- PV from LDS
    __builtin_amdgcn_s_setprio(1);
#pragma unroll
    for (int tt = 0; tt < 16; ++tt) {
      int row = 16 * tt + lr;
      int ov = (row * 64 + lg * 16) ^ (((row >> 1) & 3) << 4);
      bf16x8 va = *reinterpret_cast<const bf16x8*>(vbuf + ov);
      acc[tt] = __builtin_amdgcn_mfma_f32_16x16x32_bf16(va, pbu.v, acc[tt], 0, 0, 0);
    }
    __builtin_amdgcn_s_setprio(0);
    // raw barrier (no vmcnt drain): all ds_reads above were consumed by MFMAs
    // (compiler lgkmcnt waits), so waves reaching here are done with buf[cur].
    if (t < 31) {
      __builtin_amdgcn_sched_barrier(0);
      __builtin_amdgcn_s_barrier();
      __builtin_amdgcn_sched_barrier(0);
    }
  }
  lsum += __shfl_xor(lsum, 16, 64);
  lsum += __shfl_xor(lsum, 32, 64);

  // ---- fused epilogue: hout -> (wo projection) + bo + x -> fp32 out
  const unsigned short* wob = wbf + 196608;
  {
    float inv = 1.f / lsum;
    unsigned hp[16][2];
#pragma unroll
    for (int tt = 0; tt < 16; ++tt) {
      float h0 = acc[tt][0] * inv, h1 = acc[tt][1] * inv;
      float h2 = acc[tt][2] * inv, h3 = acc[tt][3] * inv;
      asm("v_cvt_pk_bf16_f32 %0, %1, %2" : "=v"(hp[tt][0]) : "v"(h0), "v"(h1));
      asm("v_cvt_pk_bf16_f32 %0, %1, %2" : "=v"(hp[tt][1]) : "v"(h2), "v"(h3));
    }
    int srcA = lr + 16 * ((2 * lg) & 3);
    int srcB = lr + 16 * ((2 * lg + 1) & 3);
    int hi = lg >> 1;
    bf16x8 hb[8];
#pragma unroll
    for (int kk = 0; kk < 8; ++kk) {
      unsigned a0 = __shfl(hp[2 * kk][0], srcA, 64), b0 = __shfl(hp[2 * kk + 1][0], srcA, 64);
      unsigned a1 = __shfl(hp[2 * kk][1], srcA, 64), b1 = __shfl(hp[2 * kk + 1][1], srcA, 64);
      unsigned a2 = __shfl(hp[2 * kk][0], srcB, 64), b2 = __shfl(hp[2 * kk + 1][0], srcB, 64);
      unsigned a3 = __shfl(hp[2 * kk][1], srcB, 64), b3 = __shfl(hp[2 * kk + 1][1], srcB, 64);
      union { unsigned w[4]; bf16x8 v; } u;
      u.w[0] = hi ? b0 : a0; u.w[1] = hi ? b1 : a1;
      u.w[2] = hi ? b2 : a2; u.w[3] = hi ? b3 : a3;
      hb[kk] = u.v;
    }
    int n = n0 + lr;
#pragma unroll
    for (int t = 0; t < 16; ++t) {
      f32x4 ao = {0.f, 0.f, 0.f, 0.f};
#pragma unroll
      for (int kk = 0; kk < 8; ++kk) {
        bf16x8 wf = ldb8(wob + (size_t)(16 * t + lr) * Cc + 32 * kk + 8 * lg);
        ao = __builtin_amdgcn_mfma_f32_16x16x32_bf16(wf, hb[kk], ao, 0, 0, 0);
      }
      float4 bov = *reinterpret_cast<const float4*>(bo + 16 * t + 4 * lg);
#pragma unroll
      for (int r = 0; r < 4; ++r) {
        int o = 16 * t + 4 * lg + r;
        size_t idx = (size_t)o * Nn + n;
        ob[idx] = xb[idx] + ((const float*)&bov)[r] + ao[r];
      }
    }
  }
}

extern "C" void kernel_launch(void* const* d_in, const int* in_sizes, int n_in,
                              void* d_out, int out_size, void* d_ws, size_t ws_size,
                              hipStream_t stream) {
  const float* x  = (const float*)d_in[0];
  const float* gw = (const float*)d_in[1];
  const float* gb = (const float*)d_in[2];
  const float* wq = (const float*)d_in[3];
  const float* bq = (const float*)d_in[4];
  const float* wk = (const float*)d_in[5];
  const float* bk = (const float*)d_in[6];
  const float* wv = (const float*)d_in[7];
  const float* bv = (const float*)d_in[8];
  const float* wo = (const float*)d_in[9];
  const float* bo = (const float*)d_in[10];
  float* out = (float*)d_out;
  char* ws = (char*)d_ws;

  // workspace layout — NEVER exceed ws_size:
  //   [0, 512KB)   wbf: 4 weight matrices bf16
  //   [1MB, 17MB)  hT [B,N,C] bf16
  //   [17MB, ...)  K^T/V^T staging for BG batches (BG*1MB), BG adapted to ws_size
  unsigned short* wbf = (unsigned short*)ws;
  unsigned short* hT  = (unsigned short*)(ws + (1 << 20));
  const size_t KV_OFF = (size_t)17 << 20;
  const size_t perBatchKV = (size_t)Nn * Cc * 2 * 2;  // 1MB (KT + VT)
  size_t avail = ws_size > KV_OFF ? ws_size - KV_OFF : 0;
  int BG = 32;
  while (BG > 1 && (size_t)BG * perBatchKV > avail) BG >>= 1;

  gn_cvt_kernel<<<dim3(1280), dim3(256), 0, stream>>>(x, gw, gb, hT, wq, wk, wv, wo, wbf);

  unsigned short* KTg = (unsigned short*)(ws + KV_OFF);
  unsigned short* VTg = KTg + (size_t)BG * Nn * Cc;

  for (int g = 0; g < Bb; g += BG) {
    unsigned short* hTg = hT + (size_t)g * Nn * Cc;
    kv_gemm_kernel<<<dim3(32, BG), dim3(256), 0, stream>>>(hTg, wbf, KTg, VTg, bk, bv);
    attn_fused_kernel<<<dim3(BG, 16), dim3(256), 0, stream>>>(
        wbf, bq, bo, hTg, KTg, VTg, x + (size_t)g * Cc * Nn, out + (size_t)g * Cc * Nn);
  }
}

// Round 10
// 157.750 us; speedup vs baseline: 1.1146x; 1.0334x over previous
//
#include <hip/hip_runtime.h>

typedef __attribute__((ext_vector_type(8))) short bf16x8;
typedef __attribute__((ext_vector_type(4))) float f32x4;

constexpr int Bb = 32, Cc = 256, Nn = 1024;
constexpr float EPSf = 1e-5f;
// scale 256^-0.5 with log2(e) folded in: softmax uses exp2 on pre-scaled scores
constexpr float QSCALE = 0.0625f * 1.44269504088896f;

__device__ __forceinline__ unsigned short f2bf(float f) {
  union { float f; unsigned u; } v; v.f = f;
  unsigned r = v.u + 0x7fffu + ((v.u >> 16) & 1u);
  return (unsigned short)(r >> 16);
}

__device__ __forceinline__ bf16x8 ldb8(const unsigned short* p) {
  return *reinterpret_cast<const bf16x8*>(p);
}

__device__ __forceinline__ void gload16(const void* g, void* l) {
  __builtin_amdgcn_global_load_lds((const __attribute__((address_space(1))) void*)g,
                                   (__attribute__((address_space(3))) void*)l, 16, 0, 0);
}

__device__ __forceinline__ float fexp2(float x) {
  float r;
  asm("v_exp_f32 %0, %1" : "=v"(r) : "v"(x));
  return r;
}

// ---------------- fused groupnorm (+ weight cvt piggybacked on spare blocks) ----------------
__global__ void __launch_bounds__(256) gn_cvt_kernel(
    const float* __restrict__ x, const float* __restrict__ gw, const float* __restrict__ gb,
    unsigned short* __restrict__ hT,
    const float* __restrict__ wq, const float* __restrict__ wk,
    const float* __restrict__ wv, const float* __restrict__ wo,
    unsigned short* __restrict__ wbf) {
  __shared__ float xs[8192];
  __shared__ float red[8];
  if (blockIdx.x >= 1024) {
    int i = (blockIdx.x - 1024) * 256 + threadIdx.x;
    wbf[i]          = f2bf(wq[i]);
    wbf[65536 + i]  = f2bf(wk[i]);
    wbf[131072 + i] = f2bf(wv[i]);
    wbf[196608 + i] = f2bf(wo[i]);
    return;
  }
  int b = blockIdx.x >> 5, g = blockIdx.x & 31;
  const float4* xg = (const float4*)(x + ((size_t)b * 32 + g) * 8192);
  float s = 0.f, ss = 0.f;
  for (int i = threadIdx.x; i < 2048; i += 256) {
    float4 v = xg[i];
    ((float4*)xs)[i] = v;
    s += v.x + v.y + v.z + v.w;
    ss += v.x * v.x + v.y * v.y + v.z * v.z + v.w * v.w;
  }
  for (int o = 1; o < 64; o <<= 1) { s += __shfl_xor(s, o, 64); ss += __shfl_xor(ss, o, 64); }
  int wid = threadIdx.x >> 6;
  if ((threadIdx.x & 63) == 0) { red[wid] = s; red[4 + wid] = ss; }
  __syncthreads();
  float S  = red[0] + red[1] + red[2] + red[3];
  float SS = red[4] + red[5] + red[6] + red[7];
  float mean = S * (1.f / 8192.f);
  float rstd = rsqrtf(SS * (1.f / 8192.f) - mean * mean + EPSf);
  float w8[8], b8[8];
#pragma unroll
  for (int c = 0; c < 8; ++c) {
    w8[c] = gw[g * 8 + c] * rstd;
    b8[c] = gb[g * 8 + c] - mean * w8[c];
  }
  unsigned short* ob = hT + (size_t)b * Nn * Cc + g * 8;
#pragma unroll
  for (int k = 0; k < 4; ++k) {
    int n = threadIdx.x + 256 * k;
    union { unsigned short u[8]; uint4 v; } pk;
#pragma unroll
    for (int c = 0; c < 8; ++c) pk.u[c] = f2bf(xs[c * 1024 + n] * w8[c] + b8[c]);
    *reinterpret_cast<uint4*>(ob + (size_t)n * Cc) = pk.v;
  }
}

// ---------------- bf16 GEMM tile body; two store modes ----------------
// mode 0: O bf16 row-major [row][ldo]  (K^T)
// mode 1: O fp8 e4m3, fragment-linear tile layout for attention V:
//   byte(ch=row, m=col) = (m>>5)*8192 + (ch>>4)*512 + ((ch&15) + 16*((m&31)>>3))*8 + (m&7)
__device__ __forceinline__ void gemm_tile(
    const unsigned short* __restrict__ A, const unsigned short* __restrict__ Bt,
    unsigned short* __restrict__ O, unsigned char* __restrict__ O8,
    const float* __restrict__ bias, int biasRow, int mode,
    int lda, int ldb, int ldo, int row0base, int col0base) {
  int lane = threadIdx.x & 63, wid = threadIdx.x >> 6;
  int lr = lane & 15, lg = lane >> 4;
  int row0 = row0base + (wid >> 1) * 64;
  int col0 = col0base + (wid & 1) * 64;
  f32x4 acc[4][4] = {};
  for (int k0 = 0; k0 < 256; k0 += 32) {
    bf16x8 a[4], bb[4];
#pragma unroll
    for (int i = 0; i < 4; ++i) a[i] = ldb8(A + (size_t)(row0 + 16 * i + lr) * lda + k0 + 8 * lg);
#pragma unroll
    for (int j = 0; j < 4; ++j) bb[j] = ldb8(Bt + (size_t)(col0 + 16 * j + lr) * ldb + k0 + 8 * lg);
#pragma unroll
    for (int i = 0; i < 4; ++i)
#pragma unroll
      for (int j = 0; j < 4; ++j)
        acc[i][j] = __builtin_amdgcn_mfma_f32_16x16x32_bf16(a[i], bb[j], acc[i][j], 0, 0, 0);
  }
#pragma unroll
  for (int i = 0; i < 4; ++i)
#pragma unroll
    for (int j = 0; j < 4; ++j)
#pragma unroll
      for (int r = 0; r < 4; ++r) {
        int row = row0 + 16 * i + 4 * lg + r;
        int col = col0 + 16 * j + lr;
        float v = acc[i][j][r] + (biasRow ? bias[row] : bias[col]);
        if (mode == 0) {
          O[(size_t)row * ldo + col] = f2bf(v);
        } else {
          int pk = __builtin_amdgcn_cvt_pk_fp8_f32(v, v, 0, false);
          size_t a8 = (size_t)(col >> 5) * 8192 + (size_t)(row >> 4) * 512 +
                      (size_t)((row & 15) + 16 * ((col >> 3) & 3)) * 8 + (col & 7);
          O8[a8] = (unsigned char)(pk & 0xff);
        }
      }
}

// K and V projections in one launch. grid (32, BG):
//   id<16: KT bf16 [N][C]   id>=16: VT fp8 fragment-linear tiles
__global__ void __launch_bounds__(256) kv_gemm_kernel(
    const unsigned short* __restrict__ hT, const unsigned short* __restrict__ wbf,
    unsigned short* __restrict__ KT, unsigned char* __restrict__ VT,
    const float* __restrict__ bk, const float* __restrict__ bv) {
  int bz = blockIdx.y;
  const unsigned short* h = hT + (size_t)bz * Nn * Cc;
  int id = blockIdx.x;
  if (id < 16) {
    gemm_tile(h, wbf + 65536, KT + (size_t)bz * Nn * Cc, nullptr, bk, 0, 0,
              Cc, Cc, Cc, (id >> 1) * 128, (id & 1) * 128);
  } else {
    int i2 = id - 16;
    gemm_tile(wbf + 131072, h, nullptr, VT + (size_t)bz * 262144, bv, 1, 1,
              Cc, Cc, Nn, (i2 >> 3) * 128, (i2 & 7) * 128);
  }
}

// ---------------- fused Q-proj + flash attention + out-proj + residual ----------------
// grid (BG, 16) batch-major; 256 thr = 4 waves, 16 q-cols/wave (QK), 64-ch slice (PV).
// LDS 53.5KB -> 3 blocks/CU (12 waves). Per iter: QK (bf16, verified path) ->
// P written to LDS (fp8, the write IS the redistribution; no bpermutes) -> barrier ->
// channel-split PV (fp8 MFMA): each wave reads only its 64-ch V slice for all 64 cols.
__global__ void __launch_bounds__(256, 3) attn_fused_kernel(
    const unsigned short* __restrict__ wbf, const float* __restrict__ bq,
    const float* __restrict__ bo, const unsigned short* __restrict__ hT,
    const unsigned short* __restrict__ KT, const unsigned char* __restrict__ VT,
    const float* __restrict__ x, float* __restrict__ out) {
  int b = blockIdx.x;
  int tid = threadIdx.x;
  int lane = tid & 63, wid = tid >> 6;
  int lr = lane & 15, lg = lane >> 4;
  int n0 = blockIdx.y * 64 + wid * 16;
  const unsigned short* hrow = hT + ((size_t)b * Nn + n0 + lr) * Cc;
  const char* KTb = (const char*)(KT + (size_t)b * Nn * Cc);
  const char* VTb = (const char*)(VT + (size_t)b * 262144);
  const float* xb = x + (size_t)b * Cc * Nn;
  float* ob = out + (size_t)b * Cc * Nn;

  // LDS: [0,16K) K buf0 | [16K,32K) K buf1 (bf16 [32 rows][512B], XOR-swizzled)
  //      [32K,40K) V buf0 | [40K,48K) V buf1 (fp8 fragment-linear, 8KB)
  //      [48K,50K)=49152.. actually: P buf0 [49152,51200)?? -> laid out below
  //      [49152,51200) P buf0+buf1 (2x2KB fp8 frag-linear) | [53248,53504) lsum
  //      epilogue reuses [0,32K) for hout bf16 [64 col][512B] (swizzled)
  __shared__ alignas(16) char lds[53504];

  auto stage = [&](int t, int buf) {
    // K: 32 rows x 512B bf16; read-side XOR swizzle realized by inverse-swizzled source
    char* kdst = lds + buf * 16384;
    const char* kg = KTb + (size_t)t * 16384;
#pragma unroll
    for (int r = 0; r < 4; ++r) {
      int Lb = r * 4096 + wid * 1024;
      int L = Lb + lane * 16;
      int lk = L ^ (((L >> 9) & 7) << 4);
      gload16(kg + lk, kdst + Lb);
    }
    // V: 8KB fp8, already fragment-linear in global -> pure linear copy
    char* vdst = lds + 32768 + buf * 8192;
    const char* vg = VTb + (size_t)t * 8192;
#pragma unroll
    for (int r = 0; r < 2; ++r) {
      int Lb = r * 4096 + wid * 1024;
      gload16(vg + Lb + lane * 16, vdst + Lb);
    }
  };

  stage(0, 0);  // overlaps with Q projection (no LDS use below)

  // ---- Q projection into bf16 B-fragment registers (verified path, unchanged)
  bf16x8 q[8];
  {
    bf16x8 hfrag[8];
#pragma unroll
    for (int kk = 0; kk < 8; ++kk) hfrag[kk] = ldb8(hrow + 32 * kk + 8 * lg);
    unsigned wqp[16][2];
#pragma unroll
    for (int t = 0; t < 16; ++t) {
      f32x4 aq = {0.f, 0.f, 0.f, 0.f};
#pragma unroll
      for (int kk = 0; kk < 8; ++kk) {
        bf16x8 wf = ldb8(wbf + (size_t)(16 * t + lr) * Cc + 32 * kk + 8 * lg);
        aq = __builtin_amdgcn_mfma_f32_16x16x32_bf16(wf, hfrag[kk], aq, 0, 0, 0);
      }
      float4 bqv = *reinterpret_cast<const float4*>(bq + 16 * t + 4 * lg);
      float q0 = (aq[0] + bqv.x) * QSCALE, q1 = (aq[1] + bqv.y) * QSCALE;
      float q2 = (aq[2] + bqv.z) * QSCALE, q3 = (aq[3] + bqv.w) * QSCALE;
      asm("v_cvt_pk_bf16_f32 %0, %1, %2" : "=v"(wqp[t][0]) : "v"(q0), "v"(q1));
      asm("v_cvt_pk_bf16_f32 %0, %1, %2" : "=v"(wqp[t][1]) : "v"(q2), "v"(q3));
    }
    int srcA = lr + 16 * ((2 * lg) & 3);
    int srcB = lr + 16 * ((2 * lg + 1) & 3);
    int hi = lg >> 1;
#pragma unroll
    for (int kk = 0; kk < 8; ++kk) {
      unsigned a0 = __shfl(wqp[2 * kk][0], srcA, 64), b0 = __shfl(wqp[2 * kk + 1][0], srcA, 64);
      unsigned a1 = __shfl(wqp[2 * kk][1], srcA, 64), b1 = __shfl(wqp[2 * kk + 1][1], srcA, 64);
      unsigned a2 = __shfl(wqp[2 * kk][0], srcB, 64), b2 = __shfl(wqp[2 * kk + 1][0], srcB, 64);
      unsigned a3 = __shfl(wqp[2 * kk][1], srcB, 64), b3 = __shfl(wqp[2 * kk + 1][1], srcB, 64);
      union { unsigned w[4]; bf16x8 v; } u;
      u.w[0] = hi ? b0 : a0; u.w[1] = hi ? b1 : a1;
      u.w[2] = hi ? b2 : a2; u.w[3] = hi ? b3 : a3;
      q[kk] = u.v;
    }
  }
  __syncthreads();  // tile0 staged (vmcnt drained at barrier)

  f32x4 acc[4][4] = {};  // [cht][colt]: ch = wid*64+cht*16+4lg+r, col = colt*16+lr
  float lsum = 0.f;      // per-lane partial denominator for own col (n0+lr)
  for (int t = 0; t < 32; ++t) {
    int cur = t & 1;
    if (t < 31) stage(t + 1, cur ^ 1);
    const char* kbuf = lds + cur * 16384;
    // ---- QK^T from LDS (bf16, swizzled reads — verified path)
    f32x4 st0 = {0.f, 0.f, 0.f, 0.f}, st1 = {0.f, 0.f, 0.f, 0.f};
    __builtin_amdgcn_s_setprio(1);
#pragma unroll
    for (int kk = 0; kk < 8; ++kk) {
      int c = kk * 64 + lg * 16;
      int sx = (lr & 7) << 4;
      bf16x8 k0 = *reinterpret_cast<const bf16x8*>(kbuf + ((lr * 512 + c) ^ sx));
      bf16x8 k1 = *reinterpret_cast<const bf16x8*>(kbuf + (((lr + 16) * 512 + c) ^ sx));
      st0 = __builtin_amdgcn_mfma_f32_16x16x32_bf16(k0, q[kk], st0, 0, 0, 0);
      st1 = __builtin_amdgcn_mfma_f32_16x16x32_bf16(k1, q[kk], st1, 0, 0, 0);
    }
    __builtin_amdgcn_s_setprio(0);
    // lane holds S^T[m=4lg+r (+16)][col=n0+lr]; p = exp2(s), fixed max 0
    float p0[4], p1[4];
#pragma unroll
    for (int r = 0; r < 4; ++r) {
      p0[r] = fexp2(st0[r]);
      p1[r] = fexp2(st1[r]);
    }
    lsum += ((p0[0] + p0[1]) + (p0[2] + p0[3])) + ((p1[0] + p1[1]) + (p1[2] + p1[3]));
    // ---- P -> fp8, write own values into frag-linear P LDS (no shuffles needed):
    // P[col][m] slot: byte = colT*512 + ((col&15)+16*(m>>3))*8 + (m&7)
    int u0 = __builtin_amdgcn_cvt_pk_fp8_f32(p0[0], p0[1], 0, false);
    u0 = __builtin_amdgcn_cvt_pk_fp8_f32(p0[2], p0[3], u0, true);   // m = 4lg..4lg+3
    int u1 = __builtin_amdgcn_cvt_pk_fp8_f32(p1[0], p1[1], 0, false);
    u1 = __builtin_amdgcn_cvt_pk_fp8_f32(p1[2], p1[3], u1, true);   // m = 16+4lg..+3
    {
      char* pw = lds + 49152 + cur * 2048 + wid * 512 +
                 (lr + 16 * (lg >> 1)) * 8 + 4 * (lg & 1);
      *reinterpret_cast<int*>(pw) = u0;
      *reinterpret_cast<int*>(pw + 256) = u1;  // m-chunk +2
    }
    __syncthreads();  // publish P(t); drain stage(t+1)
    // ---- channel-split PV (fp8): all 64 cols x this wave's 64-ch slice
    const char* vb = lds + 32768 + cur * 8192;
    const char* pb = lds + 49152 + cur * 2048;
    long long Pf[4], Vf[4];
#pragma unroll
    for (int ct = 0; ct < 4; ++ct)
      Pf[ct] = *reinterpret_cast<const long long*>(pb + ct * 512 + lane * 8);
#pragma unroll
    for (int ch = 0; ch < 4; ++ch)
      Vf[ch] = *reinterpret_cast<const long long*>(vb + (wid * 4 + ch) * 512 + lane * 8);
    __builtin_amdgcn_s_setprio(1);
#pragma unroll
    for (int ch = 0; ch < 4; ++ch)
#pragma unroll
      for (int ct = 0; ct < 4; ++ct)
        acc[ch][ct] = __builtin_amdgcn_mfma_f32_16x16x32_fp8_fp8(Vf[ch], Pf[ct], acc[ch][ct], 0, 0, 0);
    __builtin_amdgcn_s_setprio(0);
    __syncthreads();  // V(t)/P(t) consumed by all waves before reuse
  }
  // finalize denominators: all lanes get total for col lr of their wave
  lsum += __shfl_xor(lsum, 16, 64);
  lsum += __shfl_xor(lsum, 32, 64);
  if (lg == 0) *reinterpret_cast<float*>(lds + 53248 + (wid * 16 + lr) * 4) = lsum;
  __syncthreads();
  float inv[4];
#pragma unroll
  for (int ct = 0; ct < 4; ++ct)
    inv[ct] = 1.f / *reinterpret_cast<const float*>(lds + 53248 + (ct * 16 + lr) * 4);

  // ---- exchange hout via LDS: bf16 [64 col][256 ch], 512B rows, swizzle ^((col&7)<<4)
#pragma unroll
  for (int ch = 0; ch < 4; ++ch)
#pragma unroll
    for (int ct = 0; ct < 4; ++ct) {
      float h0 = acc[ch][ct][0] * inv[ct], h1 = acc[ch][ct][1] * inv[ct];
      float h2 = acc[ch][ct][2] * inv[ct], h3 = acc[ch][ct][3] * inv[ct];
      unsigned w0, w1;
      asm("v_cvt_pk_bf16_f32 %0, %1, %2" : "=v"(w0) : "v"(h0), "v"(h1));
      asm("v_cvt_pk_bf16_f32 %0, %1, %2" : "=v"(w1) : "v"(h2), "v"(h3));
      int col = ct * 16 + lr;
      int chb = wid * 128 + ch * 32 + 8 * lg;  // (ch index)*2 bytes
      int off = (col * 512 + chb) ^ ((col & 7) << 4);
      *reinterpret_cast<uint2*>(lds + off) = make_uint2(w0, w1);
    }
  __syncthreads();

  // ---- out-projection + bias + residual (each wave projects its own 16 cols)
  const unsigned short* wob = wbf + 196608;
  {
    int col = wid * 16 + lr;
    bf16x8 hb[8];
#pragma unroll
    for (int kk = 0; kk < 8; ++kk) {
      int off = (col * 512 + 64 * kk + 16 * lg) ^ ((lr & 7) << 4);
      hb[kk] = *reinterpret_cast<const bf16x8*>(lds + off);
    }
    int n = n0 + lr;
#pragma unroll
    for (int t = 0; t < 16; ++t) {
      f32x4 ao = {0.f, 0.f, 0.f, 0.f};
#pragma unroll
      for (int kk = 0; kk < 8; ++kk) {
        bf16x8 wf = ldb8(wob + (size_t)(16 * t + lr) * Cc + 32 * kk + 8 * lg);
        ao = __builtin_amdgcn_mfma_f32_16x16x32_bf16(wf, hb[kk], ao, 0, 0, 0);
      }
      float4 bov = *reinterpret_cast<const float4*>(bo + 16 * t + 4 * lg);
#pragma unroll
      for (int r = 0; r < 4; ++r) {
        int o = 16 * t + 4 * lg + r;
        size_t idx = (size_t)o * Nn + n;
        ob[idx] = xb[idx] + ((const float*)&bov)[r] + ao[r];
      }
    }
  }
}

extern "C" void kernel_launch(void* const* d_in, const int* in_sizes, int n_in,
                              void* d_out, int out_size, void* d_ws, size_t ws_size,
                              hipStream_t stream) {
  const float* x  = (const float*)d_in[0];
  const float* gw = (const float*)d_in[1];
  const float* gb = (const float*)d_in[2];
  const float* wq = (const float*)d_in[3];
  const float* bq = (const float*)d_in[4];
  const float* wk = (const float*)d_in[5];
  const float* bk = (const float*)d_in[6];
  const float* wv = (const float*)d_in[7];
  const float* bv = (const float*)d_in[8];
  const float* wo = (const float*)d_in[9];
  const float* bo = (const float*)d_in[10];
  float* out = (float*)d_out;
  char* ws = (char*)d_ws;

  // workspace layout — NEVER exceed ws_size:
  //   [0, 512KB)   wbf: 4 weight matrices bf16
  //   [1MB, 17MB)  hT [B,N,C] bf16
  //   [17MB, ...)  K^T bf16 (512KB/batch) + V^T fp8 frag (256KB/batch) for BG batches
  unsigned short* wbf = (unsigned short*)ws;
  unsigned short* hT  = (unsigned short*)(ws + (1 << 20));
  const size_t KV_OFF = (size_t)17 << 20;
  const size_t perBatchKV = 524288 + 262144;  // 768KB
  size_t avail = ws_size > KV_OFF ? ws_size - KV_OFF : 0;
  int BG = 32;
  while (BG > 1 && (size_t)BG * perBatchKV > avail) BG >>= 1;

  gn_cvt_kernel<<<dim3(1280), dim3(256), 0, stream>>>(x, gw, gb, hT, wq, wk, wv, wo, wbf);

  unsigned short* KTg = (unsigned short*)(ws + KV_OFF);
  unsigned char*  VTg = (unsigned char*)(ws + KV_OFF + (size_t)BG * 524288);

  for (int g = 0; g < Bb; g += BG) {
    unsigned short* hTg = hT + (size_t)g * Nn * Cc;
    kv_gemm_kernel<<<dim3(32, BG), dim3(256), 0, stream>>>(hTg, wbf, KTg, VTg, bk, bv);
    attn_fused_kernel<<<dim3(BG, 16), dim3(256), 0, stream>>>(
        wbf, bq, bo, hTg, KTg, VTg, x + (size_t)g * Cc * Nn, out + (size_t)g * Cc * Nn);
  }
}